// Round 2
// baseline (125981.030 us; speedup 1.0000x reference)
//
#include <hip/hip_runtime.h>
#include <cmath>

#define B_    2
#define S_    2048
#define H_    4096
#define NH_   32
#define NKV_  8
#define D_    128
#define QKV_N 6144
#define MTOK  4096

typedef __attribute__((ext_vector_type(8))) short bf16x8;
typedef __attribute__((ext_vector_type(4))) float f32x4;
typedef __attribute__((ext_vector_type(4))) unsigned short us4;

#define GLL16(gp, lp)                                                         \
  __builtin_amdgcn_global_load_lds(                                           \
      (const __attribute__((address_space(1))) void*)(gp),                    \
      (__attribute__((address_space(3))) void*)(lp), 16, 0, 0)

__device__ __forceinline__ unsigned short f2bf(float f) {
  unsigned u = __float_as_uint(f);
  u += 0x7fff + ((u >> 16) & 1);   // round-to-nearest-even
  return (unsigned short)(u >> 16);
}

// ---------- float -> bf16 cast (vectorized) ----------
__global__ __launch_bounds__(256) void cast_bf16_kernel(const float* __restrict__ in,
                                                        unsigned short* __restrict__ out,
                                                        int n4) {
  int i = blockIdx.x * blockDim.x + threadIdx.x;
  if (i >= n4) return;
  float4 v = ((const float4*)in)[i];
  us4 o;
  o.x = f2bf(v.x); o.y = f2bf(v.y); o.z = f2bf(v.z); o.w = f2bf(v.w);
  ((us4*)out)[i] = o;
}

// ---------- w (K x N fp32, row-major) -> wt (N x K bf16, row-major) ----------
__global__ __launch_bounds__(256) void transpose_cast_kernel(const float* __restrict__ w,
                                                             unsigned short* __restrict__ wt,
                                                             int K, int N) {
  __shared__ float tile[32][33];
  const int k0 = blockIdx.y * 32, n0 = blockIdx.x * 32;
  const int tid = threadIdx.x;
  const int r = tid >> 3, c4 = (tid & 7) * 4;
  float4 v = *(const float4*)(w + (size_t)(k0 + r) * N + n0 + c4);
  tile[r][c4 + 0] = v.x; tile[r][c4 + 1] = v.y;
  tile[r][c4 + 2] = v.z; tile[r][c4 + 3] = v.w;
  __syncthreads();
  us4 o;
  o.x = f2bf(tile[c4 + 0][r]);
  o.y = f2bf(tile[c4 + 1][r]);
  o.z = f2bf(tile[c4 + 2][r]);
  o.w = f2bf(tile[c4 + 3][r]);
  *(us4*)(wt + (size_t)(n0 + r) * K + k0 + c4) = o;
}

// ---------- bf16 MFMA GEMM (m97 structure): A MxK, Bt NxK, C MxN fp32 ----------
__global__ __launch_bounds__(256) void gemm_bt_kernel(const unsigned short* __restrict__ A,
                                                      const unsigned short* __restrict__ Bt,
                                                      float* __restrict__ C,
                                                      int M, int N, int K) {
  __shared__ short As[128 * 32];
  __shared__ short Bs[128 * 32];
  const int tid = threadIdx.x;
  const int w = tid >> 6, lane = tid & 63;
  const int quad = lane >> 4, l16 = lane & 15;
  const int bm = blockIdx.y, bn = blockIdx.x;
  const int mbase = (w & 1) * 64, nbase = (w >> 1) * 64;

  f32x4 acc[4][4] = {};

  // staging: wave w covers rows [w*32, w*32+32) of each 128x32 tile, 2 issues
  const int srow = w * 32 + (lane >> 2);
  const int skoff = (lane & 3) * 8;
  const unsigned short* Ap = A + (size_t)(bm * 128 + srow) * K + skoff;
  const unsigned short* Bp = Bt + (size_t)(bn * 128 + srow) * K + skoff;

  for (int k0 = 0; k0 < K; k0 += 32) {
    __syncthreads();
#pragma unroll
    for (int i = 0; i < 2; ++i) {
      GLL16(Ap + (size_t)i * 16 * K + k0, As + (w * 32 + i * 16) * 32);
      GLL16(Bp + (size_t)i * 16 * K + k0, Bs + (w * 32 + i * 16) * 32);
    }
    __syncthreads();
    bf16x8 af[4], bfr[4];
#pragma unroll
    for (int mi = 0; mi < 4; ++mi)
      af[mi] = *(const bf16x8*)(As + (mbase + mi * 16 + l16) * 32 + quad * 8);
#pragma unroll
    for (int nj = 0; nj < 4; ++nj)
      bfr[nj] = *(const bf16x8*)(Bs + (nbase + nj * 16 + l16) * 32 + quad * 8);
#pragma unroll
    for (int mi = 0; mi < 4; ++mi)
#pragma unroll
      for (int nj = 0; nj < 4; ++nj)
        acc[mi][nj] = __builtin_amdgcn_mfma_f32_16x16x32_bf16(af[mi], bfr[nj], acc[mi][nj], 0, 0, 0);
  }

  // C/D layout: col = lane&15, row = quad*4 + reg
  float* Cp = C + (size_t)(bm * 128 + mbase + quad * 4) * N + bn * 128 + nbase + l16;
#pragma unroll
  for (int mi = 0; mi < 4; ++mi)
#pragma unroll
    for (int nj = 0; nj < 4; ++nj)
#pragma unroll
      for (int r = 0; r < 4; ++r)
        Cp[(size_t)(mi * 16 + r) * N + nj * 16] = acc[mi][nj][r];
}

// ---------- RoPE (interleaved), in-place on q & k slices of fp32 qkv ----------
__global__ void rope_kernel(float* __restrict__ qkv, const int* __restrict__ positions) {
  int idx = blockIdx.x * blockDim.x + threadIdx.x;
  int j = idx & 63;
  int tmp = idx >> 6;
  int head = tmp % (NH_ + NKV_);
  int tok = tmp / (NH_ + NKV_);
  if (tok >= MTOK) return;
  float inv = exp2f(-(float)(2 * j) * (13.287712379549449f / 128.f));
  float f = (float)positions[tok] * inv;
  float s, c;
  sincosf(f, &s, &c);
  float* base = qkv + (size_t)tok * QKV_N + head * D_ + 2 * j;
  float x1 = base[0], x2 = base[1];
  base[0] = x1 * c - x2 * s;
  base[1] = x2 * c + x1 * s;
}

// ---------- fp32 causal GQA flash attention, 32-key tiles, swizzled LDS reads ----------
__global__ __launch_bounds__(256) void flash_attn_kernel(const float* __restrict__ qkv,
                                                         float* __restrict__ aout) {
  __shared__ float Ks[32][128];
  __shared__ float Vs[32][128];
  const int qt = (int)gridDim.x - 1 - (int)blockIdx.x;  // big blocks first
  const int h = blockIdx.y, b = blockIdx.z;
  const int kvh = h >> 2;
  const int tid = threadIdx.x;
  const int qr = tid >> 2, seg = tid & 3;
  const int qrow = qt * 64 + qr;

  const float* qptr = qkv + (size_t)(b * S_ + qrow) * QKV_N + h * D_ + seg * 32;
  float qv[32];
#pragma unroll
  for (int i = 0; i < 32; i += 4) *(float4*)&qv[i] = *(const float4*)(qptr + i);

  float m = -1e30f, l = 0.f;
  float oacc[32];
#pragma unroll
  for (int i = 0; i < 32; ++i) oacc[i] = 0.f;

  const int ntiles = 2 * qt + 2;
  for (int kt = 0; kt < ntiles; ++kt) {
    __syncthreads();
#pragma unroll
    for (int i = 0; i < 4; ++i) {
      int li = tid + i * 256;            // 1024 float4 = 32 rows x 128 floats
      int r = li >> 5, c = (li & 31) * 4;
      const float* kp = qkv + (size_t)(b * S_ + kt * 32 + r) * QKV_N + NH_ * D_ + kvh * D_ + c;
      *(float4*)&Ks[r][c] = *(const float4*)kp;
      *(float4*)&Vs[r][c] = *(const float4*)(kp + NKV_ * D_);
    }
    __syncthreads();
    const bool diag = (kt >= 2 * qt);
    const int kb = kt * 32;
    float sc[32];
#pragma unroll
    for (int kk = 0; kk < 32; ++kk) {
      float d = 0.f;
      const float* kr = &Ks[kk][seg * 32];
#pragma unroll
      for (int t = 0; t < 8; ++t) {
        int i4 = t ^ seg;                // bank-conflict-free order across segs
        float4 k4 = *(const float4*)(kr + i4 * 4);
        d = fmaf(qv[i4 * 4 + 0], k4.x, d);
        d = fmaf(qv[i4 * 4 + 1], k4.y, d);
        d = fmaf(qv[i4 * 4 + 2], k4.z, d);
        d = fmaf(qv[i4 * 4 + 3], k4.w, d);
      }
      d += __shfl_xor(d, 1);
      d += __shfl_xor(d, 2);
      d *= 0.08838834764831845f;        // 1/sqrt(128)
      if (diag && kb + kk > qrow) d = -1e30f;
      sc[kk] = d;
    }
    float cmax = sc[0];
#pragma unroll
    for (int kk = 1; kk < 32; ++kk) cmax = fmaxf(cmax, sc[kk]);
    float mn = fmaxf(m, cmax);
    float alpha = __expf(m - mn);
    m = mn;
    l *= alpha;
#pragma unroll
    for (int i = 0; i < 32; ++i) oacc[i] *= alpha;
    float psum = 0.f;
#pragma unroll
    for (int kk = 0; kk < 32; ++kk) {
      float p = __expf(sc[kk] - mn);
      psum += p;
      const float* vr = &Vs[kk][seg * 32];
#pragma unroll
      for (int t = 0; t < 8; ++t) {
        int i4 = t ^ seg;
        float4 v4 = *(const float4*)(vr + i4 * 4);
        oacc[i4 * 4 + 0] = fmaf(p, v4.x, oacc[i4 * 4 + 0]);
        oacc[i4 * 4 + 1] = fmaf(p, v4.y, oacc[i4 * 4 + 1]);
        oacc[i4 * 4 + 2] = fmaf(p, v4.z, oacc[i4 * 4 + 2]);
        oacc[i4 * 4 + 3] = fmaf(p, v4.w, oacc[i4 * 4 + 3]);
      }
    }
    l += psum;
  }
  float inv_l = 1.f / l;
  float* op = aout + (size_t)(b * S_ + qrow) * (NH_ * D_) + h * D_ + seg * 32;
#pragma unroll
  for (int i4 = 0; i4 < 8; ++i4) {
    float4 o4;
    o4.x = oacc[i4 * 4 + 0] * inv_l;
    o4.y = oacc[i4 * 4 + 1] * inv_l;
    o4.z = oacc[i4 * 4 + 2] * inv_l;
    o4.w = oacc[i4 * 4 + 3] * inv_l;
    *(float4*)(op + i4 * 4) = o4;
  }
}

extern "C" void kernel_launch(void* const* d_in, const int* in_sizes, int n_in,
                              void* d_out, int out_size, void* d_ws, size_t ws_size,
                              hipStream_t stream) {
  const float* hs    = (const float*)d_in[0];
  const int*   pos   = (const int*)d_in[1];
  const float* w_qkv = (const float*)d_in[2];
  const float* w_o   = (const float*)d_in[3];
  float* out = (float*)d_out;

  // workspace layout (bytes):
  //  [0)                qkv fp32      4096x6144x4 = 100.7 MB
  //  [A)                aout fp32     4096x4096x4 =  67.1 MB
  //  [B)                hs_bf16 then w_o^T bf16    =  33.6 MB
  //  [C)                w_qkv^T bf16 then aout_bf16 = 50.3 MB
  char* wsp = (char*)d_ws;
  float* qkv  = (float*)wsp;
  float* aout = (float*)(wsp + (size_t)MTOK * QKV_N * 4);
  unsigned short* bufB = (unsigned short*)(wsp + (size_t)MTOK * QKV_N * 4 + (size_t)MTOK * H_ * 4);
  unsigned short* bufC = bufB + (size_t)MTOK * H_;

  // 1) cast hs -> bf16 [B]; transpose-cast w_qkv -> [C]
  cast_bf16_kernel<<<(MTOK * H_ / 4 + 255) / 256, 256, 0, stream>>>(hs, bufB, MTOK * H_ / 4);
  {
    dim3 g(QKV_N / 32, H_ / 32);
    transpose_cast_kernel<<<g, 256, 0, stream>>>(w_qkv, bufC, H_, QKV_N);
  }

  // 2) qkv = hs @ w_qkv (bf16 MFMA), fp32 out
  {
    dim3 g(QKV_N / 128, MTOK / 128);
    gemm_bt_kernel<<<g, 256, 0, stream>>>(bufB, bufC, qkv, MTOK, QKV_N, H_);
  }

  // 3) RoPE on q and k heads (fp32)
  rope_kernel<<<MTOK * (NH_ + NKV_) * (D_ / 2) / 256, 256, 0, stream>>>(qkv, pos);

  // 4) causal GQA flash attention (fp32)
  {
    dim3 ga(S_ / 64, NH_, B_);
    flash_attn_kernel<<<ga, 256, 0, stream>>>(qkv, aout);
  }

  // 5) transpose-cast w_o -> [B]; cast aout -> bf16 [C]
  {
    dim3 g(H_ / 32, H_ / 32);
    transpose_cast_kernel<<<g, 256, 0, stream>>>(w_o, bufB, H_, H_);
  }
  cast_bf16_kernel<<<(MTOK * H_ / 4 + 255) / 256, 256, 0, stream>>>(aout, bufC, MTOK * H_ / 4);

  // 6) out = aout @ w_o (bf16 MFMA), fp32 out
  {
    dim3 g(H_ / 128, MTOK / 128);
    gemm_bt_kernel<<<g, 256, 0, stream>>>(bufC, bufB, out, MTOK, H_, NH_ * D_);
  }
}

// Round 3
// 4180.920 us; speedup vs baseline: 30.1324x; 30.1324x over previous
//
#include <hip/hip_runtime.h>
#include <cmath>

#define B_    2
#define S_    2048
#define H_    4096
#define NH_   32
#define NKV_  8
#define D_    128
#define QKV_N 6144
#define MTOK  4096

typedef __attribute__((ext_vector_type(8))) short bf16x8;
typedef __attribute__((ext_vector_type(4))) float f32x4;
typedef __attribute__((ext_vector_type(4))) unsigned short us4;

#define GLL16(gp, lp)                                                         \
  __builtin_amdgcn_global_load_lds(                                           \
      (const __attribute__((address_space(1))) void*)(gp),                    \
      (__attribute__((address_space(3))) void*)(lp), 16, 0, 0)

__device__ __forceinline__ unsigned short f2bf(float f) {
  unsigned u = __float_as_uint(f);
  u += 0x7fff + ((u >> 16) & 1);   // round-to-nearest-even
  return (unsigned short)(u >> 16);
}

// ---------- float -> bf16 cast (vectorized) ----------
__global__ __launch_bounds__(256) void cast_bf16_kernel(const float* __restrict__ in,
                                                        unsigned short* __restrict__ out,
                                                        int n4) {
  int i = blockIdx.x * blockDim.x + threadIdx.x;
  if (i >= n4) return;
  float4 v = ((const float4*)in)[i];
  us4 o;
  o.x = f2bf(v.x); o.y = f2bf(v.y); o.z = f2bf(v.z); o.w = f2bf(v.w);
  ((us4*)out)[i] = o;
}

// ---------- w (K x N fp32, row-major) -> wt (N x K bf16, row-major) ----------
__global__ __launch_bounds__(256) void transpose_cast_kernel(const float* __restrict__ w,
                                                             unsigned short* __restrict__ wt,
                                                             int K, int N) {
  __shared__ float tile[32][33];
  const int k0 = blockIdx.y * 32, n0 = blockIdx.x * 32;
  const int tid = threadIdx.x;
  const int r = tid >> 3, c4 = (tid & 7) * 4;
  float4 v = *(const float4*)(w + (size_t)(k0 + r) * N + n0 + c4);
  tile[r][c4 + 0] = v.x; tile[r][c4 + 1] = v.y;
  tile[r][c4 + 2] = v.z; tile[r][c4 + 3] = v.w;
  __syncthreads();
  us4 o;
  o.x = f2bf(tile[c4 + 0][r]);
  o.y = f2bf(tile[c4 + 1][r]);
  o.z = f2bf(tile[c4 + 2][r]);
  o.w = f2bf(tile[c4 + 3][r]);
  *(us4*)(wt + (size_t)(n0 + r) * K + k0 + c4) = o;
}

// ---------- bf16 MFMA GEMM (m97 structure): A MxK, Bt NxK, C MxN fp32 ----------
__global__ __launch_bounds__(256) void gemm_bt_kernel(const unsigned short* __restrict__ A,
                                                      const unsigned short* __restrict__ Bt,
                                                      float* __restrict__ C,
                                                      int M, int N, int K) {
  __shared__ short As[128 * 32];
  __shared__ short Bs[128 * 32];
  const int tid = threadIdx.x;
  const int w = tid >> 6, lane = tid & 63;
  const int quad = lane >> 4, l16 = lane & 15;
  const int bm = blockIdx.y, bn = blockIdx.x;
  const int mbase = (w & 1) * 64, nbase = (w >> 1) * 64;

  f32x4 acc[4][4] = {};

  const int srow = w * 32 + (lane >> 2);
  const int skoff = (lane & 3) * 8;
  const unsigned short* Ap = A + (size_t)(bm * 128 + srow) * K + skoff;
  const unsigned short* Bp = Bt + (size_t)(bn * 128 + srow) * K + skoff;

  for (int k0 = 0; k0 < K; k0 += 32) {
    __syncthreads();
#pragma unroll
    for (int i = 0; i < 2; ++i) {
      GLL16(Ap + (size_t)i * 16 * K + k0, As + (w * 32 + i * 16) * 32);
      GLL16(Bp + (size_t)i * 16 * K + k0, Bs + (w * 32 + i * 16) * 32);
    }
    __syncthreads();
    bf16x8 af[4], bfr[4];
#pragma unroll
    for (int mi = 0; mi < 4; ++mi)
      af[mi] = *(const bf16x8*)(As + (mbase + mi * 16 + l16) * 32 + quad * 8);
#pragma unroll
    for (int nj = 0; nj < 4; ++nj)
      bfr[nj] = *(const bf16x8*)(Bs + (nbase + nj * 16 + l16) * 32 + quad * 8);
#pragma unroll
    for (int mi = 0; mi < 4; ++mi)
#pragma unroll
      for (int nj = 0; nj < 4; ++nj)
        acc[mi][nj] = __builtin_amdgcn_mfma_f32_16x16x32_bf16(af[mi], bfr[nj], acc[mi][nj], 0, 0, 0);
  }

  float* Cp = C + (size_t)(bm * 128 + mbase + quad * 4) * N + bn * 128 + nbase + l16;
#pragma unroll
  for (int mi = 0; mi < 4; ++mi)
#pragma unroll
    for (int nj = 0; nj < 4; ++nj)
#pragma unroll
      for (int r = 0; r < 4; ++r)
        Cp[(size_t)(mi * 16 + r) * N + nj * 16] = acc[mi][nj][r];
}

// ---------- RoPE (interleaved), in-place on q & k slices of fp32 qkv ----------
__global__ void rope_kernel(float* __restrict__ qkv, const int* __restrict__ positions) {
  int idx = blockIdx.x * blockDim.x + threadIdx.x;
  int j = idx & 63;
  int tmp = idx >> 6;
  int head = tmp % (NH_ + NKV_);
  int tok = tmp / (NH_ + NKV_);
  if (tok >= MTOK) return;
  float inv = exp2f(-(float)(2 * j) * (13.287712379549449f / 128.f));
  float f = (float)positions[tok] * inv;
  float s, c;
  sincosf(f, &s, &c);
  float* base = qkv + (size_t)tok * QKV_N + head * D_ + 2 * j;
  float x1 = base[0], x2 = base[1];
  base[0] = x1 * c - x2 * s;
  base[1] = x2 * c + x1 * s;
}

// swizzled physical column for logical float col c (4-aligned):
// rotate each 32-float segment by 4*segment -> the 4 segments of one chunk j
// land on 16 distinct banks.
__device__ __forceinline__ int swz(int c) {
  return (c & 96) | ((c + ((c >> 3) & 12)) & 31);
}

// ---------- fp32 causal GQA flash attention, swizzled LDS, reg-resident arrays ----------
__global__ __launch_bounds__(256) void flash_attn_kernel(const float* __restrict__ qkv,
                                                         float* __restrict__ aout) {
  __shared__ float Ks[32][128];
  __shared__ float Vs[32][128];
  const int qt = (int)gridDim.x - 1 - (int)blockIdx.x;  // big blocks first
  const int h = blockIdx.y, b = blockIdx.z;
  const int kvh = h >> 2;
  const int tid = threadIdx.x;
  const int qr = tid >> 2, seg = tid & 3;
  const int qrow = qt * 64 + qr;
  const int pbase = seg * 32;       // this seg's physical segment base
  const int rot = seg * 4;          // per-seg bank rotation

  const float* qptr = qkv + (size_t)(b * S_ + qrow) * QKV_N + h * D_ + seg * 32;
  float qv[32];
#pragma unroll
  for (int i = 0; i < 32; i += 4) *(float4*)&qv[i] = *(const float4*)(qptr + i);

  float m = -1e30f, l = 0.f;
  float oacc[32];
#pragma unroll
  for (int i = 0; i < 32; ++i) oacc[i] = 0.f;

  const int ntiles = 2 * qt + 2;
  for (int kt = 0; kt < ntiles; ++kt) {
    __syncthreads();
#pragma unroll
    for (int i = 0; i < 4; ++i) {
      int li = tid + i * 256;            // 1024 float4 = 32 rows x 128 floats
      int r = li >> 5, c = (li & 31) * 4;
      int pc = swz(c);
      const float* kp = qkv + (size_t)(b * S_ + kt * 32 + r) * QKV_N + NH_ * D_ + kvh * D_ + c;
      *(float4*)&Ks[r][pc] = *(const float4*)kp;
      *(float4*)&Vs[r][pc] = *(const float4*)(kp + NKV_ * D_);
    }
    __syncthreads();
    const bool diag = (kt >= 2 * qt);
    const int kb = kt * 32;
    float sc[32];
#pragma unroll
    for (int kk = 0; kk < 32; ++kk) {
      float d = 0.f;
      const float* kr = &Ks[kk][pbase];
#pragma unroll
      for (int j = 0; j < 8; ++j) {      // register index j: compile-time
        float4 k4 = *(const float4*)(kr + ((4 * j + rot) & 31));
        d = fmaf(qv[j * 4 + 0], k4.x, d);
        d = fmaf(qv[j * 4 + 1], k4.y, d);
        d = fmaf(qv[j * 4 + 2], k4.z, d);
        d = fmaf(qv[j * 4 + 3], k4.w, d);
      }
      d += __shfl_xor(d, 1);
      d += __shfl_xor(d, 2);
      d *= 0.08838834764831845f;        // 1/sqrt(128)
      if (diag && kb + kk > qrow) d = -1e30f;
      sc[kk] = d;
    }
    float cmax = sc[0];
#pragma unroll
    for (int kk = 1; kk < 32; ++kk) cmax = fmaxf(cmax, sc[kk]);
    float mn = fmaxf(m, cmax);
    float alpha = __expf(m - mn);
    m = mn;
    l *= alpha;
#pragma unroll
    for (int i = 0; i < 32; ++i) oacc[i] *= alpha;
    float psum = 0.f;
#pragma unroll
    for (int kk = 0; kk < 32; ++kk) {
      float p = __expf(sc[kk] - mn);
      psum += p;
      const float* vr = &Vs[kk][pbase];
#pragma unroll
      for (int j = 0; j < 8; ++j) {
        float4 v4 = *(const float4*)(vr + ((4 * j + rot) & 31));
        oacc[j * 4 + 0] = fmaf(p, v4.x, oacc[j * 4 + 0]);
        oacc[j * 4 + 1] = fmaf(p, v4.y, oacc[j * 4 + 1]);
        oacc[j * 4 + 2] = fmaf(p, v4.z, oacc[j * 4 + 2]);
        oacc[j * 4 + 3] = fmaf(p, v4.w, oacc[j * 4 + 3]);
      }
    }
    l += psum;
  }
  float inv_l = 1.f / l;
  float* op = aout + (size_t)(b * S_ + qrow) * (NH_ * D_) + h * D_ + seg * 32;
#pragma unroll
  for (int j = 0; j < 8; ++j) {
    float4 o4;
    o4.x = oacc[j * 4 + 0] * inv_l;
    o4.y = oacc[j * 4 + 1] * inv_l;
    o4.z = oacc[j * 4 + 2] * inv_l;
    o4.w = oacc[j * 4 + 3] * inv_l;
    *(float4*)(op + j * 4) = o4;
  }
}

extern "C" void kernel_launch(void* const* d_in, const int* in_sizes, int n_in,
                              void* d_out, int out_size, void* d_ws, size_t ws_size,
                              hipStream_t stream) {
  const float* hs    = (const float*)d_in[0];
  const int*   pos   = (const int*)d_in[1];
  const float* w_qkv = (const float*)d_in[2];
  const float* w_o   = (const float*)d_in[3];
  float* out = (float*)d_out;

  char* wsp = (char*)d_ws;
  float* qkv  = (float*)wsp;
  float* aout = (float*)(wsp + (size_t)MTOK * QKV_N * 4);
  unsigned short* bufB = (unsigned short*)(wsp + (size_t)MTOK * QKV_N * 4 + (size_t)MTOK * H_ * 4);
  unsigned short* bufC = bufB + (size_t)MTOK * H_;

  // 1) cast hs -> bf16 [B]; transpose-cast w_qkv -> [C]
  cast_bf16_kernel<<<(MTOK * H_ / 4 + 255) / 256, 256, 0, stream>>>(hs, bufB, MTOK * H_ / 4);
  {
    dim3 g(QKV_N / 32, H_ / 32);
    transpose_cast_kernel<<<g, 256, 0, stream>>>(w_qkv, bufC, H_, QKV_N);
  }

  // 2) qkv = hs @ w_qkv (bf16 MFMA), fp32 out
  {
    dim3 g(QKV_N / 128, MTOK / 128);
    gemm_bt_kernel<<<g, 256, 0, stream>>>(bufB, bufC, qkv, MTOK, QKV_N, H_);
  }

  // 3) RoPE on q and k heads (fp32)
  rope_kernel<<<MTOK * (NH_ + NKV_) * (D_ / 2) / 256, 256, 0, stream>>>(qkv, pos);

  // 4) causal GQA flash attention (fp32)
  {
    dim3 ga(S_ / 64, NH_, B_);
    flash_attn_kernel<<<ga, 256, 0, stream>>>(qkv, aout);
  }

  // 5) transpose-cast w_o -> [B]; cast aout -> bf16 [C]
  {
    dim3 g(H_ / 32, H_ / 32);
    transpose_cast_kernel<<<g, 256, 0, stream>>>(w_o, bufB, H_, H_);
  }
  cast_bf16_kernel<<<(MTOK * H_ / 4 + 255) / 256, 256, 0, stream>>>(aout, bufC, MTOK * H_ / 4);

  // 6) out = aout @ w_o (bf16 MFMA), fp32 out
  {
    dim3 g(H_ / 128, MTOK / 128);
    gemm_bt_kernel<<<g, 256, 0, stream>>>(bufC, bufB, out, MTOK, H_, NH_ * D_);
  }
}